// Round 20
// baseline (647.301 us; speedup 1.0000x reference)
//
#include <hip/hip_runtime.h>
#include <math.h>

#define NN 10000
#define HIDD 256
#define MTOK 8
#define TT 3
#define EE 160000
#define AA 2000
#define OUTD 10
#define LNEPS 1e-5f

typedef unsigned short u16;
typedef __attribute__((ext_vector_type(8))) __bf16 bf16x8;
typedef __attribute__((ext_vector_type(4))) float f32x4;
typedef __attribute__((ext_vector_type(8))) unsigned short u16x8;

__device__ __forceinline__ float gelu_f(float x) {
    return 0.5f * x * (1.f + erff(x * 0.7071067811865475f));
}
__device__ __forceinline__ u16 f2bf(float x) {
    unsigned u = __builtin_bit_cast(unsigned, x);
    return (u16)((u + 0x7FFFu + ((u >> 16) & 1u)) >> 16);
}
__device__ __forceinline__ float bf2f(u16 b) {
    return __builtin_bit_cast(float, (unsigned)b << 16);
}
__device__ __forceinline__ void gload16(const void* g, void* l) {
    __builtin_amdgcn_global_load_lds(
        (const __attribute__((address_space(1))) unsigned int*)g,
        (__attribute__((address_space(3))) unsigned int*)l, 16, 0, 0);
}

// ---------------- graph build (batched over 2 graphs) ----------------
__global__ void count_kernel(const int* __restrict__ edge, int* __restrict__ cnt) {
    int g = blockIdx.y;
    const int* dst = edge + (size_t)g * 2 * EE + EE;
    int e = blockIdx.x * 256 + threadIdx.x;
    if (e < EE) atomicAdd(&cnt[g * NN + dst[e]], 1);
}

__global__ __launch_bounds__(1024) void scan_kernel(const int* __restrict__ cnt_all,
        int* __restrict__ rowstart_all, int* __restrict__ cursor_all, float* __restrict__ dinv_all) {
    int g = blockIdx.x;
    const int* cnt = cnt_all + (size_t)g * NN;
    int* rowstart = rowstart_all + (size_t)g * NN;
    int* cursor = cursor_all + (size_t)g * NN;
    float* dinv = dinv_all + (size_t)g * NN;
    __shared__ int wsum[16];
    int tid = threadIdx.x, lane = tid & 63, wid = tid >> 6;
    int carry = 0;
    for (int base = 0; base < NN; base += 1024) {
        int i = base + tid;
        int v = (i < NN) ? cnt[i] : 0;
        int s = v;
        #pragma unroll
        for (int o = 1; o < 64; o <<= 1) {
            int t = __shfl_up(s, o, 64);
            if (lane >= o) s += t;
        }
        if (lane == 63) wsum[wid] = s;
        __syncthreads();
        if (wid == 0) {
            int ws = (lane < 16) ? wsum[lane] : 0;
            #pragma unroll
            for (int o = 1; o < 16; o <<= 1) {
                int t = __shfl_up(ws, o, 64);
                if (lane >= o) ws += t;
            }
            if (lane < 16) wsum[lane] = ws;
        }
        __syncthreads();
        int woff = (wid > 0) ? wsum[wid - 1] : 0;
        int tot = wsum[15];
        if (i < NN) {
            int excl = carry + s + woff - v;
            rowstart[i] = excl;
            cursor[i] = excl;
            dinv[i] = rsqrtf((float)(v + 1));
        }
        carry += tot;
        __syncthreads();
    }
}

__global__ void fill_kernel(const int* __restrict__ edge, int* __restrict__ cursor, int* __restrict__ esrc) {
    int g = blockIdx.y;
    const int* src = edge + (size_t)g * 2 * EE;
    const int* dst = src + EE;
    int e = blockIdx.x * 256 + threadIdx.x;
    if (e < EE) {
        int d = dst[e];
        int idx = atomicAdd(&cursor[g * NN + d], 1);
        esrc[(size_t)g * EE + idx] = src[e];
    }
}

// ---------------- GCN aggregation, batched over 2 graphs (4-way unrolled gather) ----------------
template<int RELU, int WF32, int WSPLIT>
__global__ __launch_bounds__(256) void gcn_agg(const float* __restrict__ xw, size_t xw_goff,
        const int* __restrict__ esrc_all, const int* __restrict__ rowstart_all,
        const int* __restrict__ cnt_all, const float* __restrict__ dinv_all,
        const float* __restrict__ bias, float* __restrict__ out,
        u16* __restrict__ ohi, u16* __restrict__ olo) {
    int g = blockIdx.y;
    const float* xwg = xw + (size_t)g * xw_goff;
    const int* esrc = esrc_all + (size_t)g * EE;
    const int* rowstart = rowstart_all + (size_t)g * NN;
    const int* cntp = cnt_all + (size_t)g * NN;
    const float* dinv = dinv_all + (size_t)g * NN;
    int wave = threadIdx.x >> 6, lane = threadIdx.x & 63;
    int d = blockIdx.x * 4 + wave;
    if (d >= NN) return;
    int start = rowstart[d];
    int len = cntp[d];
    float dd = dinv[d];
    int h = lane * 4;
    float4 a = *(const float4*)&xwg[(size_t)d * HIDD + h];
    float4 a0, a1, a2, a3;
    a0.x = a.x * dd; a0.y = a.y * dd; a0.z = a.z * dd; a0.w = a.w * dd;
    a1.x = 0.f; a1.y = 0.f; a1.z = 0.f; a1.w = 0.f;
    a2 = a1; a3 = a1;
    int i = 0;
    for (; i + 4 <= len; i += 4) {
        int s0 = esrc[start + i];
        int s1 = esrc[start + i + 1];
        int s2 = esrc[start + i + 2];
        int s3 = esrc[start + i + 3];
        float d0 = dinv[s0], d1 = dinv[s1], d2 = dinv[s2], d3 = dinv[s3];
        float4 b0 = *(const float4*)&xwg[(size_t)s0 * HIDD + h];
        float4 b1 = *(const float4*)&xwg[(size_t)s1 * HIDD + h];
        float4 b2 = *(const float4*)&xwg[(size_t)s2 * HIDD + h];
        float4 b3 = *(const float4*)&xwg[(size_t)s3 * HIDD + h];
        a0.x = fmaf(b0.x, d0, a0.x); a1.x = fmaf(b1.x, d1, a1.x);
        a2.x = fmaf(b2.x, d2, a2.x); a3.x = fmaf(b3.x, d3, a3.x);
        a0.y = fmaf(b0.y, d0, a0.y); a1.y = fmaf(b1.y, d1, a1.y);
        a2.y = fmaf(b2.y, d2, a2.y); a3.y = fmaf(b3.y, d3, a3.y);
        a0.z = fmaf(b0.z, d0, a0.z); a1.z = fmaf(b1.z, d1, a1.z);
        a2.z = fmaf(b2.z, d2, a2.z); a3.z = fmaf(b3.z, d3, a3.z);
        a0.w = fmaf(b0.w, d0, a0.w); a1.w = fmaf(b1.w, d1, a1.w);
        a2.w = fmaf(b2.w, d2, a2.w); a3.w = fmaf(b3.w, d3, a3.w);
    }
    for (; i < len; i++) {
        int s0 = esrc[start + i];
        float d0 = dinv[s0];
        float4 b0 = *(const float4*)&xwg[(size_t)s0 * HIDD + h];
        a0.x = fmaf(b0.x, d0, a0.x);
        a0.y = fmaf(b0.y, d0, a0.y);
        a0.z = fmaf(b0.z, d0, a0.z);
        a0.w = fmaf(b0.w, d0, a0.w);
    }
    float4 acc;
    acc.x = (a0.x + a1.x) + (a2.x + a3.x);
    acc.y = (a0.y + a1.y) + (a2.y + a3.y);
    acc.z = (a0.z + a1.z) + (a2.z + a3.z);
    acc.w = (a0.w + a1.w) + (a2.w + a3.w);
    float o0 = acc.x * dd + bias[h + 0];
    float o1 = acc.y * dd + bias[h + 1];
    float o2 = acc.z * dd + bias[h + 2];
    float o3 = acc.w * dd + bias[h + 3];
    if (RELU) {
        o0 = fmaxf(o0, 0.f); o1 = fmaxf(o1, 0.f); o2 = fmaxf(o2, 0.f); o3 = fmaxf(o3, 0.f);
    }
    size_t obase = (size_t)g * NN * HIDD + (size_t)d * HIDD + h;
    if (WF32) {
        float4 o; o.x = o0; o.y = o1; o.z = o2; o.w = o3;
        *(float4*)&out[obase] = o;
    }
    if (WSPLIT) {
        ushort4 hv, lv;
        u16 h0 = f2bf(o0), h1 = f2bf(o1), h2 = f2bf(o2), h3 = f2bf(o3);
        hv.x = h0; hv.y = h1; hv.z = h2; hv.w = h3;
        lv.x = f2bf(o0 - bf2f(h0)); lv.y = f2bf(o1 - bf2f(h1));
        lv.z = f2bf(o2 - bf2f(h2)); lv.w = f2bf(o3 - bf2f(h3));
        *(ushort4*)&ohi[obase] = hv;
        *(ushort4*)&olo[obase] = lv;
    }
}

__global__ void mask_kernel(const int* __restrict__ node_t, float* __restrict__ xs) {
    int g = blockIdx.y;
    int node = node_t[(size_t)g * AA + blockIdx.x];
    xs[(size_t)g * NN * HIDD + (size_t)node * HIDD + threadIdx.x] = 0.f;
}

// ---------------- splits ----------------
__global__ void split_kernel(const float* __restrict__ x, u16* __restrict__ hi, u16* __restrict__ lo, int n) {
    int i = blockIdx.x * 256 + threadIdx.x;
    if (i < n) {
        float v = x[i];
        u16 h = f2bf(v);
        hi[i] = h;
        lo[i] = f2bf(v - bf2f(h));
    }
}

// W[256,256] -> Bt[256][768] = [Whi^T | Whi^T | Wlo^T]
__global__ void wsplit_all(const float* __restrict__ w0, const float* __restrict__ w1,
        const float* __restrict__ w2, const float* __restrict__ w3,
        const float* __restrict__ w4, const float* __restrict__ w5, u16* __restrict__ bt) {
    const float* W[6] = { w0, w1, w2, w3, w4, w5 };
    const float* Wm = W[blockIdx.y];
    u16* Bt = bt + (size_t)blockIdx.y * 256 * 768;
    int c = blockIdx.x, k = threadIdx.x;
    float x = Wm[k * 256 + c];
    u16 hi = f2bf(x), lo = f2bf(x - bf2f(hi));
    Bt[c * 768 + k] = hi;
    Bt[c * 768 + 256 + k] = hi;
    Bt[c * 768 + 512 + k] = lo;
}

// ---------------- split-bf16 MFMA GEMM, paired-phase (8 phases, 16 barriers) ----------------
template<int ACT, int WF32, int WSPLIT, int EPI>
__global__ __launch_bounds__(256) void gemm_split(
        const u16* __restrict__ Ahi, const u16* __restrict__ Alo,
        const u16* __restrict__ Bt, const float* __restrict__ bias,
        float* __restrict__ outf, u16* __restrict__ ohi, u16* __restrict__ olo,
        const float* __restrict__ xsum, int R) {
    __shared__ __align__(16) u16 ldsAhi[2][128 * 64];
    __shared__ __align__(16) u16 ldsAlo[128 * 64];
    __shared__ __align__(16) u16 ldsB[2][128 * 64];
    int tid = threadIdx.x;
    int lane = tid & 63, w = tid >> 6;
    int nwg = gridDim.x, orig = blockIdx.x;
    int xcd = orig & 7, i8 = orig >> 3;
    int q = nwg >> 3, r = nwg & 7;
    int bid = (xcd < r ? xcd * (q + 1) : r * (q + 1) + (xcd - r) * q) + i8;
    int rowbase = (bid >> 1) * 128;
    int cb = bid & 1;
    int wrow = (w >> 1) * 64, wcol = (w & 1) * 64;
    f32x4 acc[4][4];
    #pragma unroll
    for (int i = 0; i < 4; i++)
        #pragma unroll
        for (int j = 0; j < 4; j++) acc[i][j] = f32x4{0.f, 0.f, 0.f, 0.f};

    auto stageAhi = [&](int slot, int k) {
        int koff = k * 64;
        #pragma unroll
        for (int i = 0; i < 4; i++) {
            int j = i * 256 + tid;
            int rr = j >> 3, sl = j & 7;
            int grow = rowbase + rr; if (grow > R - 1) grow = R - 1;
            const u16* gp = Ahi + (size_t)grow * 256 + koff + ((sl ^ (rr & 7)) << 3);
            gload16(gp, &ldsAhi[slot][(i * 256 + (tid & 192)) << 3]);
        }
    };
    auto stageAlo = [&](int k) {
        int koff = k * 64;
        #pragma unroll
        for (int i = 0; i < 4; i++) {
            int j = i * 256 + tid;
            int rr = j >> 3, sl = j & 7;
            int grow = rowbase + rr; if (grow > R - 1) grow = R - 1;
            const u16* gp = Alo + (size_t)grow * 256 + koff + ((sl ^ (rr & 7)) << 3);
            gload16(gp, &ldsAlo[(i * 256 + (tid & 192)) << 3]);
        }
    };
    auto stageB = [&](int buf, int c) {
        #pragma unroll
        for (int i = 0; i < 4; i++) {
            int j = i * 256 + tid;
            int rr = j >> 3, sl = j & 7;
            const u16* gp = Bt + (size_t)(cb * 128 + rr) * 768 + c * 64 + ((sl ^ (rr & 7)) << 3);
            gload16(gp, &ldsB[buf][(i * 256 + (tid & 192)) << 3]);
        }
    };

    stageAhi(0, 0);
    stageAlo(0);
    stageB(0, 0);
    #pragma unroll
    for (int k = 0; k < 4; k++) {
        int sh = k & 1;
        stageB(1, 8 + k);
        asm volatile("s_waitcnt vmcnt(4)" ::: "memory");
        __builtin_amdgcn_s_barrier();
        __builtin_amdgcn_sched_barrier(0);
        __builtin_amdgcn_s_setprio(1);
        #pragma unroll
        for (int ks = 0; ks < 2; ks++) {
            bf16x8 ah[4], al[4], b[4];
            #pragma unroll
            for (int rf = 0; rf < 4; rf++) {
                int rr = wrow + rf * 16 + (lane & 15);
                int slot = (lane >> 4) + ks * 4;
                int offi = (rr << 6) + ((slot ^ (rr & 7)) << 3);
                ah[rf] = *(const bf16x8*)&ldsAhi[sh][offi];
                al[rf] = *(const bf16x8*)&ldsAlo[offi];
            }
            #pragma unroll
            for (int cf = 0; cf < 4; cf++) {
                int cc = wcol + cf * 16 + (lane & 15);
                int slot = (lane >> 4) + ks * 4;
                b[cf] = *(const bf16x8*)&ldsB[0][(cc << 6) + ((slot ^ (cc & 7)) << 3)];
            }
            #pragma unroll
            for (int rf = 0; rf < 4; rf++)
                #pragma unroll
                for (int cf = 0; cf < 4; cf++) {
                    acc[rf][cf] = __builtin_amdgcn_mfma_f32_16x16x32_bf16(ah[rf], b[cf], acc[rf][cf], 0, 0, 0);
                    acc[rf][cf] = __builtin_amdgcn_mfma_f32_16x16x32_bf16(al[rf], b[cf], acc[rf][cf], 0, 0, 0);
                }
        }
        __builtin_amdgcn_s_setprio(0);
        __builtin_amdgcn_sched_barrier(0);
        __builtin_amdgcn_s_barrier();
        if (k < 3) {
            stageAhi(sh ^ 1, k + 1);
            stageAlo(k + 1);
            stageB(0, k + 1);
            asm volatile("s_waitcnt vmcnt(12)" ::: "memory");
        } else {
            asm volatile("s_waitcnt vmcnt(0)" ::: "memory");
        }
        __builtin_amdgcn_s_barrier();
        __builtin_amdgcn_sched_barrier(0);
        __builtin_amdgcn_s_setprio(1);
        #pragma unroll
        for (int ks = 0; ks < 2; ks++) {
            bf16x8 a[4], b[4];
            #pragma unroll
            for (int rf = 0; rf < 4; rf++) {
                int rr = wrow + rf * 16 + (lane & 15);
                int slot = (lane >> 4) + ks * 4;
                a[rf] = *(const bf16x8*)&ldsAhi[sh][(rr << 6) + ((slot ^ (rr & 7)) << 3)];
            }
            #pragma unroll
            for (int cf = 0; cf < 4; cf++) {
                int cc = wcol + cf * 16 + (lane & 15);
                int slot = (lane >> 4) + ks * 4;
                b[cf] = *(const bf16x8*)&ldsB[1][(cc << 6) + ((slot ^ (cc & 7)) << 3)];
            }
            #pragma unroll
            for (int rf = 0; rf < 4; rf++)
                #pragma unroll
                for (int cf = 0; cf < 4; cf++)
                    acc[rf][cf] = __builtin_amdgcn_mfma_f32_16x16x32_bf16(a[rf], b[cf], acc[rf][cf], 0, 0, 0);
        }
        __builtin_amdgcn_s_setprio(0);
        __builtin_amdgcn_sched_barrier(0);
        __builtin_amdgcn_s_barrier();
    }
    #pragma unroll
    for (int rf = 0; rf < 4; rf++) {
        #pragma unroll
        for (int cf = 0; cf < 4; cf++) {
            int col = cb * 128 + wcol + cf * 16 + (lane & 15);
            float bv = bias[col];
            f32x4 v = acc[rf][cf];
            if (EPI == 1) {
                float s = 0.f;
                #pragma unroll
                for (int r2 = 0; r2 < 4; r2++) s += gelu_f(v[r2] + bv);
                float o = __shfl_xor(s, 16, 64);
                float nodesum = s + o;
                if (((lane >> 4) & 1) == 0) {
                    int node = ((rowbase + wrow + rf * 16) >> 3) + ((lane >> 4) >> 1);
                    u16 hi = f2bf(nodesum), lo = f2bf(nodesum - bf2f(hi));
                    ohi[(size_t)node * 256 + col] = hi;
                    olo[(size_t)node * 256 + col] = lo;
                }
            } else {
                int row0 = rowbase + wrow + rf * 16 + ((lane >> 4) << 2);
                #pragma unroll
                for (int r2 = 0; r2 < 4; r2++) {
                    int row = row0 + r2;
                    if (row < R) {
                        float val = v[r2] + bv;
                        if (ACT == 1) val = gelu_f(val);
                        if (ACT == 2) val = tanhf(val);
                        if (WF32) outf[(size_t)row * 256 + col] = val;
                        if (WSPLIT) {
                            u16 hi = f2bf(val), lo = f2bf(val - bf2f(hi));
                            ohi[(size_t)row * 256 + col] = hi;
                            olo[(size_t)row * 256 + col] = lo;
                        }
                    }
                }
            }
        }
    }
}

// ---------------- FUSED tail v3: reg-staged 2-deep prefetched B (T14) ----------------
// v=(xsum+s2@cw2+8b)/8 -> h=tanh(v@pred+b) -> g=h@cls1+b -> y=relu(g@cls2+b)
// 8 B-chunks/stage {0,1,2,3,8,9,10,11}; ci<4 runs A-hi then A-lo against the same B.
__global__ __launch_bounds__(512, 2) void tail_fused(
        const u16* __restrict__ s2_hi, const u16* __restrict__ s2_lo,
        const float* __restrict__ xsum,
        const u16* __restrict__ Bt_cw2, const float* __restrict__ cb2,
        const u16* __restrict__ Bt_pred, const float* __restrict__ pred_b,
        const u16* __restrict__ Bt_cls1, const float* __restrict__ cls1_b,
        const float* __restrict__ cls2_w, const float* __restrict__ cls2_b,
        float* __restrict__ h_out1, float* __restrict__ y_out1, int R) {
    __shared__ __align__(16) u16 ldsA[2][32 * 256];
    __shared__ __align__(16) u16 ldsB[256 * 64];
    int tid = threadIdx.x;
    int lane = tid & 63, wid = tid >> 6;
    int wrow = (wid & 1) * 16, wcol = (wid >> 1) * 64;
    int nwg = gridDim.x, orig = blockIdx.x;
    int xcd = orig & 7, i8 = orig >> 3;
    int q = nwg >> 3, r = nwg & 7;
    int bidx = (xcd < r ? xcd * (q + 1) : r * (q + 1) + (xcd - r) * q) + i8;
    int rowbase = bidx * 32;

    // prologue: A = s2 split (pre-swizzled global source -> linear LDS dest)
    #pragma unroll
    for (int seg = 0; seg < 2; seg++) {
        const u16* src = seg ? s2_lo : s2_hi;
        #pragma unroll
        for (int i = 0; i < 2; i++) {
            int j = i * 512 + tid;
            int rr = j >> 5;
            int gch = (j >> 3) & 3, t = j & 7;
            int rowG = rowbase + rr; if (rowG > R - 1) rowG = R - 1;
            const u16* gp = src + (size_t)rowG * 256 + gch * 64 + ((t ^ (rr & 7)) << 3);
            gload16(gp, &ldsA[seg][(i * 512 + (tid & 448)) << 3]);
        }
    }

    constexpr int CL[8] = {0, 1, 2, 3, 8, 9, 10, 11};
    for (int s = 0; s < 3; s++) {
        const u16* Bt = (s == 0) ? Bt_cw2 : (s == 1) ? Bt_pred : Bt_cls1;
        uint4 rb0[4], rb1[4];
        auto loadB = [&](uint4* rr_, int c) {
            #pragma unroll
            for (int i = 0; i < 4; i++) {
                int j = i * 512 + tid;
                int cc = j >> 3, sl = j & 7;
                rr_[i] = *(const uint4*)(Bt + (size_t)cc * 768 + c * 64 + ((sl ^ (cc & 7)) << 3));
            }
        };
        auto writeB = [&](const uint4* rr_) {
            #pragma unroll
            for (int i = 0; i < 4; i++) {
                int j = i * 512 + tid;
                *(uint4*)&ldsB[(size_t)j * 8] = rr_[i];
            }
        };
        loadB(rb0, CL[0]);
        loadB(rb1, CL[1]);
        f32x4 acc[4];
        #pragma unroll
        for (int i = 0; i < 4; i++) acc[i] = f32x4{0.f, 0.f, 0.f, 0.f};
        #pragma unroll
        for (int ci = 0; ci < 8; ci++) {
            // all waves done reading previous B chunk (and stage-entry ldsA epilogue writes drained)
            asm volatile("s_waitcnt lgkmcnt(0)" ::: "memory");
            __builtin_amdgcn_s_barrier();
            if (ci & 1) {
                writeB(rb1);                       // compiler inserts counted vmcnt wait for rb1
                if (ci + 2 < 8) loadB(rb1, CL[ci + 2]);
            } else {
                writeB(rb0);
                if (ci + 2 < 8) loadB(rb0, CL[ci + 2]);
            }
            asm volatile("s_waitcnt lgkmcnt(0)" ::: "memory");
            __builtin_amdgcn_s_barrier();
            __builtin_amdgcn_sched_barrier(0);
            __builtin_amdgcn_s_setprio(1);
            int kbase = (ci < 4 ? ci : ci - 4) * 64;
            // group 1: A-hi
            #pragma unroll
            for (int ks = 0; ks < 2; ks++) {
                int rr = wrow + (lane & 15);
                int slot = (lane >> 4) + ks * 4;
                bf16x8 a = *(const bf16x8*)&ldsA[0][rr * 256 + kbase + ((slot ^ (rr & 7)) << 3)];
                #pragma unroll
                for (int cf = 0; cf < 4; cf++) {
                    int cc = wcol + cf * 16 + (lane & 15);
                    bf16x8 b = *(const bf16x8*)&ldsB[cc * 64 + ((slot ^ (cc & 7)) << 3)];
                    acc[cf] = __builtin_amdgcn_mfma_f32_16x16x32_bf16(a, b, acc[cf], 0, 0, 0);
                }
            }
            // group 2 (chunks 0-3 only): A-lo against the same B
            if (ci < 4) {
                #pragma unroll
                for (int ks = 0; ks < 2; ks++) {
                    int rr = wrow + (lane & 15);
                    int slot = (lane >> 4) + ks * 4;
                    bf16x8 a = *(const bf16x8*)&ldsA[1][rr * 256 + kbase + ((slot ^ (rr & 7)) << 3)];
                    #pragma unroll
                    for (int cf = 0; cf < 4; cf++) {
                        int cc = wcol + cf * 16 + (lane & 15);
                        bf16x8 b = *(const bf16x8*)&ldsB[cc * 64 + ((slot ^ (cc & 7)) << 3)];
                        acc[cf] = __builtin_amdgcn_mfma_f32_16x16x32_bf16(a, b, acc[cf], 0, 0, 0);
                    }
                }
            }
            __builtin_amdgcn_s_setprio(0);
            __builtin_amdgcn_sched_barrier(0);
        }
        __builtin_amdgcn_s_barrier();   // all reads of A complete before in-place overwrite
        #pragma unroll
        for (int cf = 0; cf < 4; cf++) {
            int col = wcol + cf * 16 + (lane & 15);
            #pragma unroll
            for (int r2 = 0; r2 < 4; r2++) {
                int row = wrow + ((lane >> 4) << 2) + r2;
                int rowG = rowbase + row;
                int rowC = rowG > R - 1 ? R - 1 : rowG;
                float av = acc[cf][r2];
                int pos = row * 256 + (col >> 6) * 64 + ((((col >> 3) & 7) ^ (row & 7)) << 3) + (col & 7);
                if (s == 0) {
                    float val = (xsum[(size_t)rowC * 256 + col] + av + 8.f * cb2[col]) * 0.125f;
                    u16 hi = f2bf(val), lo = f2bf(val - bf2f(hi));
                    ldsA[0][pos] = hi;
                    ldsA[1][pos] = lo;
                } else if (s == 1) {
                    float h = tanhf(av + pred_b[col]);
                    if (rowG < R) h_out1[(size_t)rowG * 256 + col] = h;
                    u16 hi = f2bf(h), lo = f2bf(h - bf2f(hi));
                    ldsA[0][pos] = hi;
                    ldsA[1][pos] = lo;
                } else {
                    ((float*)ldsA)[row * 256 + (col ^ (row & 31))] = av + cls1_b[col];
                }
            }
        }
    }
    float* w2 = (float*)ldsB;
    for (int i = tid; i < 256 * OUTD; i += 512) w2[i] = cls2_w[i];
    asm volatile("s_waitcnt lgkmcnt(0) vmcnt(0)" ::: "memory");
    __builtin_amdgcn_s_barrier();
    const float* gbuf = (const float*)ldsA;
    for (int o = tid; o < 32 * OUTD; o += 512) {
        int row = o / OUTD, j = o - row * OUTD;
        int rowG = rowbase + row;
        if (rowG < R) {
            float a2 = 0.f;
            for (int k = 0; k < 256; k++) a2 = fmaf(gbuf[row * 256 + (k ^ (row & 31))], w2[k * OUTD + j], a2);
            y_out1[(size_t)rowG * OUTD + j] = fmaxf(a2 + cls2_b[j], 0.f);
        }
    }
}

// ---------------- mixer front: zero-token shortcut + vectorized z write ----------------
__global__ __launch_bounds__(256) void mixer_front(
        const float* __restrict__ xs, int nodebase,
        const float* __restrict__ ln1_g, const float* __restrict__ ln1_b,
        const float* __restrict__ tw1, const float* __restrict__ tb1,
        const float* __restrict__ tw2, const float* __restrict__ tb2,
        const float* __restrict__ ln2_g, const float* __restrict__ ln2_b,
        u16* __restrict__ z_hi, u16* __restrict__ z_lo, float* __restrict__ xsum_out) {
    int nv = nodebase + blockIdx.x;
    int step = nv >= NN ? 1 : 0;
    int n = nv - step * NN;
    const float* p1 = xs + ((size_t)step * NN + n) * HIDD;
    const float* p2 = step ? xs + (size_t)n * HIDD : nullptr;
    int tid = threadIdx.x;
    int wave = tid >> 6, lane = tid & 63;
    __shared__ __align__(16) float sx[MTOK][HIDD];
    __shared__ float stw1h[16], stw2[64], stb1[8], stb2[8], sw1s6[8];
    __shared__ float red[MTOK][2];
    if (tid < 16) stw1h[tid] = tw1[48 + tid];
    if (tid < 64) stw2[tid] = tw2[tid];
    if (tid < 8) {
        stb1[tid] = tb1[tid]; stb2[tid] = tb2[tid];
        float s = 0.f;
        #pragma unroll
        for (int m = 0; m < 6; m++) s += tw1[m * MTOK + tid];
        sw1s6[tid] = s;
    }
    sx[6][tid] = p2 ? p2[tid] : 0.f;
    sx[7][tid] = p1[tid];
    __syncthreads();
    float g1v = ln1_g[tid], b1v = ln1_b[tid];
    if (wave < 2) {
        int m = 6 + wave;
        float x0 = sx[m][lane], x1 = sx[m][lane + 64], x2 = sx[m][lane + 128], x3 = sx[m][lane + 192];
        float s = x0 + x1 + x2 + x3;
        float ss = x0 * x0 + x1 * x1 + x2 * x2 + x3 * x3;
        for (int off = 32; off > 0; off >>= 1) { s += __shfl_down(s, off, 64); ss += __shfl_down(ss, off, 64); }
        if (lane == 0) {
            float mu = s * (1.f / HIDD);
            float var = ss * (1.f / HIDD) - mu * mu;
            red[m][0] = mu;
            red[m][1] = rsqrtf(var + LNEPS);
        }
    }
    __syncthreads();
    float x6 = sx[6][tid], x7 = sx[7][tid];
    float ty6 = (x6 - red[6][0]) * red[6][1] * g1v + b1v;
    float ty7 = (x7 - red[7][0]) * red[7][1] * g1v + b1v;
    float u[MTOK];
    #pragma unroll
    for (int k = 0; k < MTOK; k++) {
        float a = stb1[k];
        a = fmaf(b1v, sw1s6[k], a);
        a = fmaf(ty6, stw1h[k], a);
        a = fmaf(ty7, stw1h[8 + k], a);
        u[k] = gelu_f(a);
    }
    float xsm = 0.f;
    #pragma unroll
    for (int k = 0; k < MTOK; k++) {
        float a = stb2[k];
        #pragma unroll
        for (int m = 0; m < MTOK; m++) a = fmaf(u[m], stw2[m * MTOK + k], a);
        if (k == 6) a += x6;
        if (k == 7) a += x7;
        sx[k][tid] = a;
        xsm += a;
    }
    xsum_out[(size_t)nv * HIDD + tid] = xsm;
    __syncthreads();
    float g2v = ln2_g[tid], b2v = ln2_b[tid];
    #pragma unroll
    for (int rep = 0; rep < 2; rep++) {
        int m = wave + rep * 4;
        float x0 = sx[m][lane], x1 = sx[m][lane + 64], x2 = sx[m][lane + 128], x3 = sx[m][lane + 192];
        float s = x0 + x1 + x2 + x3;
        float ss = x0 * x0 + x1 * x1 + x2 * x2 + x3 * x3;
        for (int off = 32; off > 0; off >>= 1) { s += __shfl_down(s, off, 64); ss += __shfl_down(ss, off, 64); }
        if (lane == 0) {
            float mu = s * (1.f / HIDD);
            float var = ss * (1.f / HIDD) - mu * mu;
            red[m][0] = mu;
            red[m][1] = rsqrtf(var + LNEPS);
        }
    }
    __syncthreads();
    #pragma unroll
    for (int m = 0; m < MTOK; m++) {
        float z = (sx[m][tid] - red[m][0]) * red[m][1] * g2v + b2v;
        sx[m][tid] = z;
    }
    __syncthreads();
    {
        int m = tid >> 5;
        int c0 = (tid & 31) << 3;
        u16x8 hv, lv;
        #pragma unroll
        for (int j = 0; j < 8; j++) {
            float z = sx[m][c0 + j];
            u16 h = f2bf(z);
            hv[j] = h;
            lv[j] = f2bf(z - bf2f(h));
        }
        size_t base = ((size_t)blockIdx.x * MTOK + m) * HIDD + c0;
        *(u16x8*)&z_hi[base] = hv;
        *(u16x8*)&z_lo[base] = lv;
    }
}

// ---------------- full f32 mixer for the (uniform) t=0 row ----------------
__global__ __launch_bounds__(256) void mixer_kernel(
        const float* __restrict__ ln1_g, const float* __restrict__ ln1_b,
        const float* __restrict__ tw1, const float* __restrict__ tb1,
        const float* __restrict__ tw2, const float* __restrict__ tb2,
        const float* __restrict__ ln2_g, const float* __restrict__ ln2_b,
        const float* __restrict__ cw1, const float* __restrict__ cb1,
        const float* __restrict__ cw2, const float* __restrict__ cb2,
        float* __restrict__ vout) {
    int tid = threadIdx.x;
    __shared__ __align__(16) float sx[MTOK][HIDD];
    __shared__ __align__(16) float sy[MTOK][HIDD];
    __shared__ float stw1[64], stw2[64], stb1[8], stb2[8];
    if (tid < 64) { stw1[tid] = tw1[tid]; stw2[tid] = tw2[tid]; }
    if (tid < 8)  { stb1[tid] = tb1[tid]; stb2[tid] = tb2[tid]; }
    __syncthreads();
    float b1v = ln1_b[tid];
    float ty[MTOK];
    #pragma unroll
    for (int m = 0; m < MTOK; m++) ty[m] = b1v;
    float u[MTOK];
    #pragma unroll
    for (int k = 0; k < MTOK; k++) {
        float a = stb1[k];
        #pragma unroll
        for (int m = 0; m < MTOK; m++) a = fmaf(ty[m], stw1[m * MTOK + k], a);
        u[k] = gelu_f(a);
    }
    #pragma unroll
    for (int k = 0; k < MTOK; k++) {
        float a = stb2[k];
        #pragma unroll
        for (int m = 0; m < MTOK; m++) a = fmaf(u[m], stw2[m * MTOK + k], a);
        sx[k][tid] = a;
    }
    __syncthreads();
    __shared__ float red[MTOK][2];
    int wave = tid >> 6, lane = tid & 63;
    float g2v = ln2_g[tid], b2v = ln2_b[tid];
    #pragma unroll
    for (int rep = 0; rep < 2; rep++) {
        int m = wave + rep * 4;
        float x0 = sx[m][lane], x1 = sx[m][lane + 64], x2 = sx[m][lane + 128], x3 = sx[m][lane + 192];
        float s = x0 + x1 + x2 + x3;
        float ss = x0 * x0 + x1 * x1 + x2 * x2 + x3 * x3;
        for (int off = 32; off > 0; off >>= 1) { s += __shfl_down(s, off, 64); ss += __shfl_down(ss, off, 64); }
        if (lane == 0) {
            float mu = s * (1.f / HIDD);
            float var = ss * (1.f / HIDD) - mu * mu;
            red[m][0] = mu;
            red[m][1] = rsqrtf(var + LNEPS);
        }
    }
    __syncthreads();
    #pragma unroll
    for (int m = 0; m < MTOK; m++) sy[m][tid] = (sx[m][tid] - red[m][0]) * red[m][1] * g2v + b2v;
    __syncthreads();
    float acc[MTOK];
    #pragma unroll
    for (int m = 0; m < MTOK; m++) acc[m] = 0.f;
    for (int h = 0; h < HIDD; h += 4) {
        float w0 = cw1[(h + 0) * HIDD + tid];
        float w1 = cw1[(h + 1) * HIDD + tid];
        float w2 = cw1[(h + 2) * HIDD + tid];
        float w3 = cw1[(h + 3) * HIDD + tid];
        #pragma unroll
        for (int m = 0; m < MTOK; m++) {
            const float4 a = *(const float4*)&sy[m][h];
            acc[m] = fmaf(a.x, w0, acc[m]);
            acc[m] = fmaf(a.y, w1, acc[m]);
            acc[m] = fmaf(a.z, w2, acc[m]);
            acc[m] = fmaf(a.w, w3, acc[m]);
        }
    }
    __syncthreads();
    float cb1v = cb1[tid];
    #pragma unroll
    for (int m = 0; m < MTOK; m++) sy[m][tid] = gelu_f(acc[m] + cb1v);
    __syncthreads();
    float acc2[MTOK];
    #pragma unroll
    for (int m = 0; m < MTOK; m++) acc2[m] = 0.f;
    for (int h = 0; h < HIDD; h += 4) {
        float w0 = cw2[(h + 0) * HIDD + tid];
        float w1 = cw2[(h + 1) * HIDD + tid];
        float w2 = cw2[(h + 2) * HIDD + tid];
        float w3 = cw2[(h + 3) * HIDD + tid];
        #pragma unroll
        for (int m = 0; m < MTOK; m++) {
            const float4 a = *(const float4*)&sy[m][h];
            acc2[m] = fmaf(a.x, w0, acc2[m]);
            acc2[m] = fmaf(a.y, w1, acc2[m]);
            acc2[m] = fmaf(a.z, w2, acc2[m]);
            acc2[m] = fmaf(a.w, w3, acc2[m]);
        }
    }
    float cb2v = cb2[tid];
    float ssum = 0.f;
    #pragma unroll
    for (int m = 0; m < MTOK; m++) ssum += sx[m][tid] + acc2[m] + cb2v;
    vout[tid] = ssum * (1.f / MTOK);
}

// ---------------- fused t=0 head ----------------
__global__ __launch_bounds__(256) void t0_head(const float* __restrict__ v0row,
        const float* __restrict__ pred_w, const float* __restrict__ pred_b,
        const float* __restrict__ cls1_w, const float* __restrict__ cls1_b,
        const float* __restrict__ cls2_w, const float* __restrict__ cls2_b,
        float* __restrict__ h0row, float* __restrict__ y0row) {
    __shared__ float s[HIDD], s2[HIDD];
    int tid = threadIdx.x;
    s[tid] = v0row[tid];
    __syncthreads();
    float a = 0.f;
    for (int k = 0; k < HIDD; k++) a = fmaf(s[k], pred_w[k * HIDD + tid], a);
    float h = tanhf(a + pred_b[tid]);
    h0row[tid] = h;
    s2[tid] = h;
    __syncthreads();
    a = 0.f;
    for (int k = 0; k < HIDD; k++) a = fmaf(s2[k], cls1_w[k * HIDD + tid], a);
    float g = a + cls1_b[tid];
    __syncthreads();
    s[tid] = g;
    __syncthreads();
    if (tid < OUTD) {
        float y = 0.f;
        for (int k = 0; k < HIDD; k++) y = fmaf(s[k], cls2_w[k * OUTD + tid], y);
        y0row[tid] = fmaxf(y + cls2_b[tid], 0.f);
    }
}

__global__ void bcast_both(const float* __restrict__ h0row, const float* __restrict__ y0row,
        float* __restrict__ hout, float* __restrict__ yout) {
    int n = blockIdx.x, tid = threadIdx.x;
    hout[(size_t)n * HIDD + tid] = h0row[tid];
    if (tid < OUTD) yout[(size_t)n * OUTD + tid] = y0row[tid];
}

extern "C" void kernel_launch(void* const* d_in, const int* in_sizes, int n_in,
                              void* d_out, int out_size, void* d_ws, size_t ws_size,
                              hipStream_t stream) {
    const int* edge    = (const int*)d_in[0];
    const int* node_t  = (const int*)d_in[1];
    const float* emb   = (const float*)d_in[3];
    const float* gcn_w1 = (const float*)d_in[4];
    const float* gcn_b1 = (const float*)d_in[5];
    const float* gcn_w2 = (const float*)d_in[6];
    const float* gcn_b2 = (const float*)d_in[7];
    const float* ln1_g = (const float*)d_in[8];
    const float* ln1_b = (const float*)d_in[9];
    const float* tw1   = (const float*)d_in[10];
    const float* tb1   = (const float*)d_in[11];
    const float* tw2   = (const float*)d_in[12];
    const float* tb2   = (const float*)d_in[13];
    const float* ln2_g = (const float*)d_in[14];
    const float* ln2_b = (const float*)d_in[15];
    const float* cw1   = (const float*)d_in[16];
    const float* cb1   = (const float*)d_in[17];
    const float* cw2   = (const float*)d_in[18];
    const float* cb2   = (const float*)d_in[19];
    const float* pred_w = (const float*)d_in[20];
    const float* pred_b = (const float*)d_in[21];
    const float* cls1_w = (const float*)d_in[22];
    const float* cls1_b = (const float*)d_in[23];
    const float* cls2_w = (const float*)d_in[24];
    const float* cls2_b = (const float*)d_in[25];

    const size_t NH = (size_t)NN * HIDD;
    char* wsb = (char*)d_ws;
    size_t off = 0;
    auto alloc = [&](size_t bytes) { char* p = wsb + off; off = (off + bytes + 255) & ~(size_t)255; return p; };
    float* xs   = (float*)alloc(2 * NH * 4);
    u16* v_hi   = (u16*)alloc(2 * NH * 2);         // GCN alias: agg_hi
    u16* v_lo   = (u16*)alloc(2 * NH * 2);         // GCN alias: agg_lo
    u16* h_hi   = (u16*)alloc(2 * NH * 2);         // PREP/GCN alias: xw (f32)
    u16* h_lo   = (u16*)alloc(2 * NH * 2);         // PREP alias: emb_hi+emb_lo
    float* xw2  = (float*)alloc(2 * NH * 4);       // GCN scratch; MIXER alias: s2
    float* xsum = (float*)alloc(2 * NH * 4);
    u16* Bt_all = (u16*)alloc((size_t)6 * 256 * 768 * 2);
    u16* Bt_cw1  = Bt_all;
    u16* Bt_cw2  = Bt_all + 1 * 256 * 768;
    u16* Bt_pred = Bt_all + 2 * 256 * 768;
    u16* Bt_cls1 = Bt_all + 3 * 256 * 768;
    u16* Bt_gw1  = Bt_all + 4 * 256 * 768;
    u16* Bt_gw2  = Bt_all + 5 * 256 * 768;
    float* dinv  = (float*)alloc(2 * NN * 4);
    float* zeros = (float*)alloc(HIDD * 4);
    float* v0row = (float*)alloc(HIDD * 4);
    float* h0row = (float*)alloc(HIDD * 4);
    float* y0row = (float*)alloc(16 * 4);
    int* cnt    = (int*)alloc(2 * NN * 4);
    int* rowst  = (int*)alloc(2 * NN * 4);
    int* cursor = (int*)alloc(2 * NN * 4);
    int* esrc   = (int*)alloc((size_t)2 * EE * 4);
    float* xw    = (float*)h_hi;
    u16*  emb_hi = h_lo;
    u16*  emb_lo = h_lo + NH;
    u16*  agg_hi = v_hi;
    u16*  agg_lo = v_lo;
    u16*  s2_hi  = (u16*)xw2;
    u16*  s2_lo  = (u16*)xw2 + 2 * NH;
    size_t remain = (ws_size > off + 4096) ? (ws_size - off - 4096) : 0;
    int CHN = (int)(remain / 8192);
    if (CHN > 2 * NN) CHN = 2 * NN;
    CHN &= ~15;
    if (CHN < 16) CHN = 16;
    const size_t ZE = (size_t)CHN * MTOK * HIDD;
    u16* z_hi  = (u16*)alloc(ZE * 2);
    u16* z_lo  = (u16*)alloc(ZE * 2);

    float* h_out = (float*)d_out;
    float* y_out = h_out + (size_t)TT * NH;

    // ---- prep ----
    hipMemsetAsync(zeros, 0, HIDD * sizeof(float), stream);
    wsplit_all<<<dim3(256, 6), 256, 0, stream>>>(cw1, cw2, pred_w, cls1_w, gcn_w1, gcn_w2, Bt_all);
    split_kernel<<<(NN * HIDD + 255) / 256, 256, 0, stream>>>(emb, emb_hi, emb_lo, NN * HIDD);
    gemm_split<0, 1, 0, 0><<<2 * ((NN + 127) / 128), 256, 0, stream>>>(
        emb_hi, emb_lo, Bt_gw1, zeros, xw, nullptr, nullptr, nullptr, NN);

    // ---- t=0 outputs (uniform) ----
    mixer_kernel<<<1, 256, 0, stream>>>(ln1_g, ln1_b, tw1, tb1, tw2, tb2,
        ln2_g, ln2_b, cw1, cb1, cw2, cb2, v0row);
    t0_head<<<1, 256, 0, stream>>>(v0row, pred_w, pred_b, cls1_w, cls1_b,
        cls2_w, cls2_b, h0row, y0row);
    bcast_both<<<NN, 256, 0, stream>>>(h0row, y0row, h_out, y_out);

    // ---- GCN for both timesteps (batched) ----
    hipMemsetAsync(cnt, 0, 2 * NN * sizeof(int), stream);
    count_kernel<<<dim3((EE + 255) / 256, 2), 256, 0, stream>>>(edge, cnt);
    scan_kernel<<<2, 1024, 0, stream>>>(cnt, rowst, cursor, dinv);
    fill_kernel<<<dim3((EE + 255) / 256, 2), 256, 0, stream>>>(edge, cursor, esrc);
    gcn_agg<1, 0, 1><<<dim3((NN + 3) / 4, 2), 256, 0, stream>>>(xw, 0,
        esrc, rowst, cnt, dinv, gcn_b1, nullptr, agg_hi, agg_lo);
    gemm_split<0, 1, 0, 0><<<2 * ((2 * NN + 127) / 128), 256, 0, stream>>>(
        agg_hi, agg_lo, Bt_gw2, zeros, xw2, nullptr, nullptr, nullptr, 2 * NN);
    gcn_agg<0, 1, 0><<<dim3((NN + 3) / 4, 2), 256, 0, stream>>>(xw2, NH,
        esrc, rowst, cnt, dinv, gcn_b2, xs, nullptr, nullptr);
    mask_kernel<<<dim3(AA, 2), 256, 0, stream>>>(node_t, xs);

    // ---- mixer for t=1,2: front + cw1 (fused gelu+token-sum epilogue) ----
    for (int nb = 0; nb < 2 * NN; nb += CHN) {
        int nodes = 2 * NN - nb < CHN ? 2 * NN - nb : CHN;
        int R = nodes * MTOK;
        int rb = (R + 127) / 128;
        mixer_front<<<nodes, 256, 0, stream>>>(xs, nb,
            ln1_g, ln1_b, tw1, tb1, tw2, tb2, ln2_g, ln2_b, z_hi, z_lo, xsum);
        gemm_split<1, 0, 0, 1><<<2 * rb, 256, 0, stream>>>(
            z_hi, z_lo, Bt_cw1, cb1, nullptr,
            s2_hi + (size_t)nb * HIDD, s2_lo + (size_t)nb * HIDD, nullptr, R);
    }
    // ---- fused tail: cw2 (+mean fold) -> pred -> cls1 -> cls2, one dispatch ----
    tail_fused<<<(2 * NN + 31) / 32, 512, 0, stream>>>(
        s2_hi, s2_lo, xsum,
        Bt_cw2, cb2, Bt_pred, pred_b, Bt_cls1, cls1_b, cls2_w, cls2_b,
        h_out + NH, y_out + (size_t)NN * OUTD, 2 * NN);
}

// Round 21
// 498.111 us; speedup vs baseline: 1.2995x; 1.2995x over previous
//
#include <hip/hip_runtime.h>
#include <math.h>

#define NN 10000
#define HIDD 256
#define MTOK 8
#define TT 3
#define EE 160000
#define AA 2000
#define OUTD 10
#define LNEPS 1e-5f

typedef unsigned short u16;
typedef __attribute__((ext_vector_type(8))) __bf16 bf16x8;
typedef __attribute__((ext_vector_type(4))) float f32x4;
typedef __attribute__((ext_vector_type(8))) unsigned short u16x8;

__device__ __forceinline__ float gelu_f(float x) {
    return 0.5f * x * (1.f + erff(x * 0.7071067811865475f));
}
__device__ __forceinline__ u16 f2bf(float x) {
    unsigned u = __builtin_bit_cast(unsigned, x);
    return (u16)((u + 0x7FFFu + ((u >> 16) & 1u)) >> 16);
}
__device__ __forceinline__ float bf2f(u16 b) {
    return __builtin_bit_cast(float, (unsigned)b << 16);
}
__device__ __forceinline__ void gload16(const void* g, void* l) {
    __builtin_amdgcn_global_load_lds(
        (const __attribute__((address_space(1))) unsigned int*)g,
        (__attribute__((address_space(3))) unsigned int*)l, 16, 0, 0);
}

// ---------------- graph build (batched over 2 graphs) ----------------
__global__ void count_kernel(const int* __restrict__ edge, int* __restrict__ cnt) {
    int g = blockIdx.y;
    const int* dst = edge + (size_t)g * 2 * EE + EE;
    int e = blockIdx.x * 256 + threadIdx.x;
    if (e < EE) atomicAdd(&cnt[g * NN + dst[e]], 1);
}

__global__ __launch_bounds__(1024) void scan_kernel(const int* __restrict__ cnt_all,
        int* __restrict__ rowstart_all, int* __restrict__ cursor_all, float* __restrict__ dinv_all) {
    int g = blockIdx.x;
    const int* cnt = cnt_all + (size_t)g * NN;
    int* rowstart = rowstart_all + (size_t)g * NN;
    int* cursor = cursor_all + (size_t)g * NN;
    float* dinv = dinv_all + (size_t)g * NN;
    __shared__ int wsum[16];
    int tid = threadIdx.x, lane = tid & 63, wid = tid >> 6;
    int carry = 0;
    for (int base = 0; base < NN; base += 1024) {
        int i = base + tid;
        int v = (i < NN) ? cnt[i] : 0;
        int s = v;
        #pragma unroll
        for (int o = 1; o < 64; o <<= 1) {
            int t = __shfl_up(s, o, 64);
            if (lane >= o) s += t;
        }
        if (lane == 63) wsum[wid] = s;
        __syncthreads();
        if (wid == 0) {
            int ws = (lane < 16) ? wsum[lane] : 0;
            #pragma unroll
            for (int o = 1; o < 16; o <<= 1) {
                int t = __shfl_up(ws, o, 64);
                if (lane >= o) ws += t;
            }
            if (lane < 16) wsum[lane] = ws;
        }
        __syncthreads();
        int woff = (wid > 0) ? wsum[wid - 1] : 0;
        int tot = wsum[15];
        if (i < NN) {
            int excl = carry + s + woff - v;
            rowstart[i] = excl;
            cursor[i] = excl;
            dinv[i] = rsqrtf((float)(v + 1));
        }
        carry += tot;
        __syncthreads();
    }
}

__global__ void fill_kernel(const int* __restrict__ edge, int* __restrict__ cursor, int* __restrict__ esrc) {
    int g = blockIdx.y;
    const int* src = edge + (size_t)g * 2 * EE;
    const int* dst = src + EE;
    int e = blockIdx.x * 256 + threadIdx.x;
    if (e < EE) {
        int d = dst[e];
        int idx = atomicAdd(&cursor[g * NN + d], 1);
        esrc[(size_t)g * EE + idx] = src[e];
    }
}

// ---------------- GCN aggregation, batched over 2 graphs (4-way unrolled gather) ----------------
template<int RELU, int WF32, int WSPLIT>
__global__ __launch_bounds__(256) void gcn_agg(const float* __restrict__ xw, size_t xw_goff,
        const int* __restrict__ esrc_all, const int* __restrict__ rowstart_all,
        const int* __restrict__ cnt_all, const float* __restrict__ dinv_all,
        const float* __restrict__ bias, float* __restrict__ out,
        u16* __restrict__ ohi, u16* __restrict__ olo) {
    int g = blockIdx.y;
    const float* xwg = xw + (size_t)g * xw_goff;
    const int* esrc = esrc_all + (size_t)g * EE;
    const int* rowstart = rowstart_all + (size_t)g * NN;
    const int* cntp = cnt_all + (size_t)g * NN;
    const float* dinv = dinv_all + (size_t)g * NN;
    int wave = threadIdx.x >> 6, lane = threadIdx.x & 63;
    int d = blockIdx.x * 4 + wave;
    if (d >= NN) return;
    int start = rowstart[d];
    int len = cntp[d];
    float dd = dinv[d];
    int h = lane * 4;
    float4 a = *(const float4*)&xwg[(size_t)d * HIDD + h];
    float4 a0, a1, a2, a3;
    a0.x = a.x * dd; a0.y = a.y * dd; a0.z = a.z * dd; a0.w = a.w * dd;
    a1.x = 0.f; a1.y = 0.f; a1.z = 0.f; a1.w = 0.f;
    a2 = a1; a3 = a1;
    int i = 0;
    for (; i + 4 <= len; i += 4) {
        int s0 = esrc[start + i];
        int s1 = esrc[start + i + 1];
        int s2 = esrc[start + i + 2];
        int s3 = esrc[start + i + 3];
        float d0 = dinv[s0], d1 = dinv[s1], d2 = dinv[s2], d3 = dinv[s3];
        float4 b0 = *(const float4*)&xwg[(size_t)s0 * HIDD + h];
        float4 b1 = *(const float4*)&xwg[(size_t)s1 * HIDD + h];
        float4 b2 = *(const float4*)&xwg[(size_t)s2 * HIDD + h];
        float4 b3 = *(const float4*)&xwg[(size_t)s3 * HIDD + h];
        a0.x = fmaf(b0.x, d0, a0.x); a1.x = fmaf(b1.x, d1, a1.x);
        a2.x = fmaf(b2.x, d2, a2.x); a3.x = fmaf(b3.x, d3, a3.x);
        a0.y = fmaf(b0.y, d0, a0.y); a1.y = fmaf(b1.y, d1, a1.y);
        a2.y = fmaf(b2.y, d2, a2.y); a3.y = fmaf(b3.y, d3, a3.y);
        a0.z = fmaf(b0.z, d0, a0.z); a1.z = fmaf(b1.z, d1, a1.z);
        a2.z = fmaf(b2.z, d2, a2.z); a3.z = fmaf(b3.z, d3, a3.z);
        a0.w = fmaf(b0.w, d0, a0.w); a1.w = fmaf(b1.w, d1, a1.w);
        a2.w = fmaf(b2.w, d2, a2.w); a3.w = fmaf(b3.w, d3, a3.w);
    }
    for (; i < len; i++) {
        int s0 = esrc[start + i];
        float d0 = dinv[s0];
        float4 b0 = *(const float4*)&xwg[(size_t)s0 * HIDD + h];
        a0.x = fmaf(b0.x, d0, a0.x);
        a0.y = fmaf(b0.y, d0, a0.y);
        a0.z = fmaf(b0.z, d0, a0.z);
        a0.w = fmaf(b0.w, d0, a0.w);
    }
    float4 acc;
    acc.x = (a0.x + a1.x) + (a2.x + a3.x);
    acc.y = (a0.y + a1.y) + (a2.y + a3.y);
    acc.z = (a0.z + a1.z) + (a2.z + a3.z);
    acc.w = (a0.w + a1.w) + (a2.w + a3.w);
    float o0 = acc.x * dd + bias[h + 0];
    float o1 = acc.y * dd + bias[h + 1];
    float o2 = acc.z * dd + bias[h + 2];
    float o3 = acc.w * dd + bias[h + 3];
    if (RELU) {
        o0 = fmaxf(o0, 0.f); o1 = fmaxf(o1, 0.f); o2 = fmaxf(o2, 0.f); o3 = fmaxf(o3, 0.f);
    }
    size_t obase = (size_t)g * NN * HIDD + (size_t)d * HIDD + h;
    if (WF32) {
        float4 o; o.x = o0; o.y = o1; o.z = o2; o.w = o3;
        *(float4*)&out[obase] = o;
    }
    if (WSPLIT) {
        ushort4 hv, lv;
        u16 h0 = f2bf(o0), h1 = f2bf(o1), h2 = f2bf(o2), h3 = f2bf(o3);
        hv.x = h0; hv.y = h1; hv.z = h2; hv.w = h3;
        lv.x = f2bf(o0 - bf2f(h0)); lv.y = f2bf(o1 - bf2f(h1));
        lv.z = f2bf(o2 - bf2f(h2)); lv.w = f2bf(o3 - bf2f(h3));
        *(ushort4*)&ohi[obase] = hv;
        *(ushort4*)&olo[obase] = lv;
    }
}

__global__ void mask_kernel(const int* __restrict__ node_t, float* __restrict__ xs) {
    int g = blockIdx.y;
    int node = node_t[(size_t)g * AA + blockIdx.x];
    xs[(size_t)g * NN * HIDD + (size_t)node * HIDD + threadIdx.x] = 0.f;
}

// ---------------- splits ----------------
__global__ void split_kernel(const float* __restrict__ x, u16* __restrict__ hi, u16* __restrict__ lo, int n) {
    int i = blockIdx.x * 256 + threadIdx.x;
    if (i < n) {
        float v = x[i];
        u16 h = f2bf(v);
        hi[i] = h;
        lo[i] = f2bf(v - bf2f(h));
    }
}

// W[256,256] -> Bt[256][768] = [Whi^T | Whi^T | Wlo^T]
__global__ void wsplit_all(const float* __restrict__ w0, const float* __restrict__ w1,
        const float* __restrict__ w2, const float* __restrict__ w3,
        const float* __restrict__ w4, const float* __restrict__ w5, u16* __restrict__ bt) {
    const float* W[6] = { w0, w1, w2, w3, w4, w5 };
    const float* Wm = W[blockIdx.y];
    u16* Bt = bt + (size_t)blockIdx.y * 256 * 768;
    int c = blockIdx.x, k = threadIdx.x;
    float x = Wm[k * 256 + c];
    u16 hi = f2bf(x), lo = f2bf(x - bf2f(hi));
    Bt[c * 768 + k] = hi;
    Bt[c * 768 + 256 + k] = hi;
    Bt[c * 768 + 512 + k] = lo;
}

// ---------------- split-bf16 MFMA GEMM, paired-phase (8 phases, 16 barriers) ----------------
template<int ACT, int WF32, int WSPLIT, int EPI>
__global__ __launch_bounds__(256) void gemm_split(
        const u16* __restrict__ Ahi, const u16* __restrict__ Alo,
        const u16* __restrict__ Bt, const float* __restrict__ bias,
        float* __restrict__ outf, u16* __restrict__ ohi, u16* __restrict__ olo,
        const float* __restrict__ xsum, int R) {
    __shared__ __align__(16) u16 ldsAhi[2][128 * 64];
    __shared__ __align__(16) u16 ldsAlo[128 * 64];
    __shared__ __align__(16) u16 ldsB[2][128 * 64];
    int tid = threadIdx.x;
    int lane = tid & 63, w = tid >> 6;
    int nwg = gridDim.x, orig = blockIdx.x;
    int xcd = orig & 7, i8 = orig >> 3;
    int q = nwg >> 3, r = nwg & 7;
    int bid = (xcd < r ? xcd * (q + 1) : r * (q + 1) + (xcd - r) * q) + i8;
    int rowbase = (bid >> 1) * 128;
    int cb = bid & 1;
    int wrow = (w >> 1) * 64, wcol = (w & 1) * 64;
    f32x4 acc[4][4];
    #pragma unroll
    for (int i = 0; i < 4; i++)
        #pragma unroll
        for (int j = 0; j < 4; j++) acc[i][j] = f32x4{0.f, 0.f, 0.f, 0.f};

    auto stageAhi = [&](int slot, int k) {
        int koff = k * 64;
        #pragma unroll
        for (int i = 0; i < 4; i++) {
            int j = i * 256 + tid;
            int rr = j >> 3, sl = j & 7;
            int grow = rowbase + rr; if (grow > R - 1) grow = R - 1;
            const u16* gp = Ahi + (size_t)grow * 256 + koff + ((sl ^ (rr & 7)) << 3);
            gload16(gp, &ldsAhi[slot][(i * 256 + (tid & 192)) << 3]);
        }
    };
    auto stageAlo = [&](int k) {
        int koff = k * 64;
        #pragma unroll
        for (int i = 0; i < 4; i++) {
            int j = i * 256 + tid;
            int rr = j >> 3, sl = j & 7;
            int grow = rowbase + rr; if (grow > R - 1) grow = R - 1;
            const u16* gp = Alo + (size_t)grow * 256 + koff + ((sl ^ (rr & 7)) << 3);
            gload16(gp, &ldsAlo[(i * 256 + (tid & 192)) << 3]);
        }
    };
    auto stageB = [&](int buf, int c) {
        #pragma unroll
        for (int i = 0; i < 4; i++) {
            int j = i * 256 + tid;
            int rr = j >> 3, sl = j & 7;
            const u16* gp = Bt + (size_t)(cb * 128 + rr) * 768 + c * 64 + ((sl ^ (rr & 7)) << 3);
            gload16(gp, &ldsB[buf][(i * 256 + (tid & 192)) << 3]);
        }
    };

    stageAhi(0, 0);
    stageAlo(0);
    stageB(0, 0);
    #pragma unroll
    for (int k = 0; k < 4; k++) {
        int sh = k & 1;
        stageB(1, 8 + k);
        asm volatile("s_waitcnt vmcnt(4)" ::: "memory");
        __builtin_amdgcn_s_barrier();
        __builtin_amdgcn_sched_barrier(0);
        __builtin_amdgcn_s_setprio(1);
        #pragma unroll
        for (int ks = 0; ks < 2; ks++) {
            bf16x8 ah[4], al[4], b[4];
            #pragma unroll
            for (int rf = 0; rf < 4; rf++) {
                int rr = wrow + rf * 16 + (lane & 15);
                int slot = (lane >> 4) + ks * 4;
                int offi = (rr << 6) + ((slot ^ (rr & 7)) << 3);
                ah[rf] = *(const bf16x8*)&ldsAhi[sh][offi];
                al[rf] = *(const bf16x8*)&ldsAlo[offi];
            }
            #pragma unroll
            for (int cf = 0; cf < 4; cf++) {
                int cc = wcol + cf * 16 + (lane & 15);
                int slot = (lane >> 4) + ks * 4;
                b[cf] = *(const bf16x8*)&ldsB[0][(cc << 6) + ((slot ^ (cc & 7)) << 3)];
            }
            #pragma unroll
            for (int rf = 0; rf < 4; rf++)
                #pragma unroll
                for (int cf = 0; cf < 4; cf++) {
                    acc[rf][cf] = __builtin_amdgcn_mfma_f32_16x16x32_bf16(ah[rf], b[cf], acc[rf][cf], 0, 0, 0);
                    acc[rf][cf] = __builtin_amdgcn_mfma_f32_16x16x32_bf16(al[rf], b[cf], acc[rf][cf], 0, 0, 0);
                }
        }
        __builtin_amdgcn_s_setprio(0);
        __builtin_amdgcn_sched_barrier(0);
        __builtin_amdgcn_s_barrier();
        if (k < 3) {
            stageAhi(sh ^ 1, k + 1);
            stageAlo(k + 1);
            stageB(0, k + 1);
            asm volatile("s_waitcnt vmcnt(12)" ::: "memory");
        } else {
            asm volatile("s_waitcnt vmcnt(0)" ::: "memory");
        }
        __builtin_amdgcn_s_barrier();
        __builtin_amdgcn_sched_barrier(0);
        __builtin_amdgcn_s_setprio(1);
        #pragma unroll
        for (int ks = 0; ks < 2; ks++) {
            bf16x8 a[4], b[4];
            #pragma unroll
            for (int rf = 0; rf < 4; rf++) {
                int rr = wrow + rf * 16 + (lane & 15);
                int slot = (lane >> 4) + ks * 4;
                a[rf] = *(const bf16x8*)&ldsAhi[sh][(rr << 6) + ((slot ^ (rr & 7)) << 3)];
            }
            #pragma unroll
            for (int cf = 0; cf < 4; cf++) {
                int cc = wcol + cf * 16 + (lane & 15);
                int slot = (lane >> 4) + ks * 4;
                b[cf] = *(const bf16x8*)&ldsB[1][(cc << 6) + ((slot ^ (cc & 7)) << 3)];
            }
            #pragma unroll
            for (int rf = 0; rf < 4; rf++)
                #pragma unroll
                for (int cf = 0; cf < 4; cf++)
                    acc[rf][cf] = __builtin_amdgcn_mfma_f32_16x16x32_bf16(a[rf], b[cf], acc[rf][cf], 0, 0, 0);
        }
        __builtin_amdgcn_s_setprio(0);
        __builtin_amdgcn_sched_barrier(0);
        __builtin_amdgcn_s_barrier();
    }
    #pragma unroll
    for (int rf = 0; rf < 4; rf++) {
        #pragma unroll
        for (int cf = 0; cf < 4; cf++) {
            int col = cb * 128 + wcol + cf * 16 + (lane & 15);
            float bv = bias[col];
            f32x4 v = acc[rf][cf];
            if (EPI == 1) {
                float s = 0.f;
                #pragma unroll
                for (int r2 = 0; r2 < 4; r2++) s += gelu_f(v[r2] + bv);
                float o = __shfl_xor(s, 16, 64);
                float nodesum = s + o;
                if (((lane >> 4) & 1) == 0) {
                    int node = ((rowbase + wrow + rf * 16) >> 3) + ((lane >> 4) >> 1);
                    u16 hi = f2bf(nodesum), lo = f2bf(nodesum - bf2f(hi));
                    ohi[(size_t)node * 256 + col] = hi;
                    olo[(size_t)node * 256 + col] = lo;
                }
            } else {
                int row0 = rowbase + wrow + rf * 16 + ((lane >> 4) << 2);
                #pragma unroll
                for (int r2 = 0; r2 < 4; r2++) {
                    int row = row0 + r2;
                    if (row < R) {
                        float val = v[r2] + bv;
                        if (ACT == 1) val = gelu_f(val);
                        if (ACT == 2) val = tanhf(val);
                        if (WF32) outf[(size_t)row * 256 + col] = val;
                        if (WSPLIT) {
                            u16 hi = f2bf(val), lo = f2bf(val - bf2f(hi));
                            ohi[(size_t)row * 256 + col] = hi;
                            olo[(size_t)row * 256 + col] = lo;
                        }
                    }
                }
            }
        }
    }
}

// ---------------- FUSED tail v2 (+XCD swizzle) ----------------
__global__ __launch_bounds__(512, 2) void tail_fused(
        const u16* __restrict__ s2_hi, const u16* __restrict__ s2_lo,
        const float* __restrict__ xsum,
        const u16* __restrict__ Bt_cw2, const float* __restrict__ cb2,
        const u16* __restrict__ Bt_pred, const float* __restrict__ pred_b,
        const u16* __restrict__ Bt_cls1, const float* __restrict__ cls1_b,
        const float* __restrict__ cls2_w, const float* __restrict__ cls2_b,
        float* __restrict__ h_out1, float* __restrict__ y_out1, int R) {
    __shared__ __align__(16) u16 ldsA[2][32 * 256];
    __shared__ __align__(16) u16 ldsB[256 * 64];
    int tid = threadIdx.x;
    int lane = tid & 63, wid = tid >> 6;
    int wrow = (wid & 1) * 16, wcol = (wid >> 1) * 64;
    int nwg = gridDim.x, orig = blockIdx.x;
    int xcd = orig & 7, i8 = orig >> 3;
    int q = nwg >> 3, r = nwg & 7;
    int bidx = (xcd < r ? xcd * (q + 1) : r * (q + 1) + (xcd - r) * q) + i8;
    int rowbase = bidx * 32;

    constexpr int KCH[12]  = {0,4,1,5,2,6,3,7,8,9,10,11};
    constexpr int BNEW[12] = {1,0,1,0,1,0,1,0,1,1,1,1};

    auto stageB = [&](int c, const u16* Bt) {
        #pragma unroll
        for (int i = 0; i < 4; i++) {
            int j = i * 512 + tid;
            int cc = j >> 3, sl = j & 7;
            const u16* gp = Bt + (size_t)cc * 768 + c * 64 + ((sl ^ (cc & 7)) << 3);
            gload16(gp, &ldsB[(i * 512 + (tid & 448)) << 3]);
        }
    };
    #pragma unroll
    for (int seg = 0; seg < 2; seg++) {
        const u16* src = seg ? s2_lo : s2_hi;
        #pragma unroll
        for (int i = 0; i < 2; i++) {
            int j = i * 512 + tid;
            int rr = j >> 5;
            int gch = (j >> 3) & 3, t = j & 7;
            int rowG = rowbase + rr; if (rowG > R - 1) rowG = R - 1;
            const u16* gp = src + (size_t)rowG * 256 + gch * 64 + ((t ^ (rr & 7)) << 3);
            gload16(gp, &ldsA[seg][(i * 512 + (tid & 448)) << 3]);
        }
    }

    for (int s = 0; s < 3; s++) {
        const u16* Bt = (s == 0) ? Bt_cw2 : (s == 1) ? Bt_pred : Bt_cls1;
        f32x4 acc[4];
        #pragma unroll
        for (int i = 0; i < 4; i++) acc[i] = f32x4{0.f, 0.f, 0.f, 0.f};
        #pragma unroll
        for (int p = 0; p < 12; p++) {
            if (BNEW[p]) {
                asm volatile("s_waitcnt lgkmcnt(0)" ::: "memory");
                __builtin_amdgcn_s_barrier();
                stageB(KCH[p], Bt);
                asm volatile("s_waitcnt vmcnt(0)" ::: "memory");
                __builtin_amdgcn_s_barrier();
            }
            __builtin_amdgcn_sched_barrier(0);
            __builtin_amdgcn_s_setprio(1);
            int c = KCH[p];
            int seg = (c >= 4 && c < 8) ? 1 : 0;
            int kbase = (c & 3) * 64;
            #pragma unroll
            for (int ks = 0; ks < 2; ks++) {
                int rr = wrow + (lane & 15);
                int slot = (lane >> 4) + ks * 4;
                bf16x8 a = *(const bf16x8*)&ldsA[seg][rr * 256 + kbase + ((slot ^ (rr & 7)) << 3)];
                #pragma unroll
                for (int cf = 0; cf < 4; cf++) {
                    int cc = wcol + cf * 16 + (lane & 15);
                    bf16x8 b = *(const bf16x8*)&ldsB[cc * 64 + ((slot ^ (cc & 7)) << 3)];
                    acc[cf] = __builtin_amdgcn_mfma_f32_16x16x32_bf16(a, b, acc[cf], 0, 0, 0);
                }
            }
            __builtin_amdgcn_s_setprio(0);
            __builtin_amdgcn_sched_barrier(0);
        }
        __builtin_amdgcn_s_barrier();
        #pragma unroll
        for (int cf = 0; cf < 4; cf++) {
            int col = wcol + cf * 16 + (lane & 15);
            #pragma unroll
            for (int r2 = 0; r2 < 4; r2++) {
                int row = wrow + ((lane >> 4) << 2) + r2;
                int rowG = rowbase + row;
                int rowC = rowG > R - 1 ? R - 1 : rowG;
                float av = acc[cf][r2];
                int pos = row * 256 + (col >> 6) * 64 + ((((col >> 3) & 7) ^ (row & 7)) << 3) + (col & 7);
                if (s == 0) {
                    float val = (xsum[(size_t)rowC * 256 + col] + av + 8.f * cb2[col]) * 0.125f;
                    u16 hi = f2bf(val), lo = f2bf(val - bf2f(hi));
                    ldsA[0][pos] = hi;
                    ldsA[1][pos] = lo;
                } else if (s == 1) {
                    float h = tanhf(av + pred_b[col]);
                    if (rowG < R) h_out1[(size_t)rowG * 256 + col] = h;
                    u16 hi = f2bf(h), lo = f2bf(h - bf2f(hi));
                    ldsA[0][pos] = hi;
                    ldsA[1][pos] = lo;
                } else {
                    ((float*)ldsA)[row * 256 + (col ^ (row & 31))] = av + cls1_b[col];
                }
            }
        }
    }
    float* w2 = (float*)ldsB;
    for (int i = tid; i < 256 * OUTD; i += 512) w2[i] = cls2_w[i];
    asm volatile("s_waitcnt lgkmcnt(0) vmcnt(0)" ::: "memory");
    __builtin_amdgcn_s_barrier();
    const float* gbuf = (const float*)ldsA;
    for (int o = tid; o < 32 * OUTD; o += 512) {
        int row = o / OUTD, j = o - row * OUTD;
        int rowG = rowbase + row;
        if (rowG < R) {
            float a2 = 0.f;
            for (int k = 0; k < 256; k++) a2 = fmaf(gbuf[row * 256 + (k ^ (row & 31))], w2[k * OUTD + j], a2);
            y_out1[(size_t)rowG * OUTD + j] = fmaxf(a2 + cls2_b[j], 0.f);
        }
    }
}

// ---------------- mixer front: zero-token shortcut + vectorized z write ----------------
__global__ __launch_bounds__(256) void mixer_front(
        const float* __restrict__ xs, int nodebase,
        const float* __restrict__ ln1_g, const float* __restrict__ ln1_b,
        const float* __restrict__ tw1, const float* __restrict__ tb1,
        const float* __restrict__ tw2, const float* __restrict__ tb2,
        const float* __restrict__ ln2_g, const float* __restrict__ ln2_b,
        u16* __restrict__ z_hi, u16* __restrict__ z_lo, float* __restrict__ xsum_out) {
    int nv = nodebase + blockIdx.x;
    int step = nv >= NN ? 1 : 0;
    int n = nv - step * NN;
    const float* p1 = xs + ((size_t)step * NN + n) * HIDD;
    const float* p2 = step ? xs + (size_t)n * HIDD : nullptr;
    int tid = threadIdx.x;
    int wave = tid >> 6, lane = tid & 63;
    __shared__ __align__(16) float sx[MTOK][HIDD];
    __shared__ float stw1h[16], stw2[64], stb1[8], stb2[8], sw1s6[8];
    __shared__ float red[MTOK][2];
    if (tid < 16) stw1h[tid] = tw1[48 + tid];
    if (tid < 64) stw2[tid] = tw2[tid];
    if (tid < 8) {
        stb1[tid] = tb1[tid]; stb2[tid] = tb2[tid];
        float s = 0.f;
        #pragma unroll
        for (int m = 0; m < 6; m++) s += tw1[m * MTOK + tid];
        sw1s6[tid] = s;
    }
    sx[6][tid] = p2 ? p2[tid] : 0.f;
    sx[7][tid] = p1[tid];
    __syncthreads();
    float g1v = ln1_g[tid], b1v = ln1_b[tid];
    if (wave < 2) {
        int m = 6 + wave;
        float x0 = sx[m][lane], x1 = sx[m][lane + 64], x2 = sx[m][lane + 128], x3 = sx[m][lane + 192];
        float s = x0 + x1 + x2 + x3;
        float ss = x0 * x0 + x1 * x1 + x2 * x2 + x3 * x3;
        for (int off = 32; off > 0; off >>= 1) { s += __shfl_down(s, off, 64); ss += __shfl_down(ss, off, 64); }
        if (lane == 0) {
            float mu = s * (1.f / HIDD);
            float var = ss * (1.f / HIDD) - mu * mu;
            red[m][0] = mu;
            red[m][1] = rsqrtf(var + LNEPS);
        }
    }
    __syncthreads();
    float x6 = sx[6][tid], x7 = sx[7][tid];
    float ty6 = (x6 - red[6][0]) * red[6][1] * g1v + b1v;
    float ty7 = (x7 - red[7][0]) * red[7][1] * g1v + b1v;
    float u[MTOK];
    #pragma unroll
    for (int k = 0; k < MTOK; k++) {
        float a = stb1[k];
        a = fmaf(b1v, sw1s6[k], a);
        a = fmaf(ty6, stw1h[k], a);
        a = fmaf(ty7, stw1h[8 + k], a);
        u[k] = gelu_f(a);
    }
    float xsm = 0.f;
    #pragma unroll
    for (int k = 0; k < MTOK; k++) {
        float a = stb2[k];
        #pragma unroll
        for (int m = 0; m < MTOK; m++) a = fmaf(u[m], stw2[m * MTOK + k], a);
        if (k == 6) a += x6;
        if (k == 7) a += x7;
        sx[k][tid] = a;
        xsm += a;
    }
    xsum_out[(size_t)nv * HIDD + tid] = xsm;
    __syncthreads();
    float g2v = ln2_g[tid], b2v = ln2_b[tid];
    #pragma unroll
    for (int rep = 0; rep < 2; rep++) {
        int m = wave + rep * 4;
        float x0 = sx[m][lane], x1 = sx[m][lane + 64], x2 = sx[m][lane + 128], x3 = sx[m][lane + 192];
        float s = x0 + x1 + x2 + x3;
        float ss = x0 * x0 + x1 * x1 + x2 * x2 + x3 * x3;
        for (int off = 32; off > 0; off >>= 1) { s += __shfl_down(s, off, 64); ss += __shfl_down(ss, off, 64); }
        if (lane == 0) {
            float mu = s * (1.f / HIDD);
            float var = ss * (1.f / HIDD) - mu * mu;
            red[m][0] = mu;
            red[m][1] = rsqrtf(var + LNEPS);
        }
    }
    __syncthreads();
    #pragma unroll
    for (int m = 0; m < MTOK; m++) {
        float z = (sx[m][tid] - red[m][0]) * red[m][1] * g2v + b2v;
        sx[m][tid] = z;
    }
    __syncthreads();
    {
        int m = tid >> 5;
        int c0 = (tid & 31) << 3;
        u16x8 hv, lv;
        #pragma unroll
        for (int j = 0; j < 8; j++) {
            float z = sx[m][c0 + j];
            u16 h = f2bf(z);
            hv[j] = h;
            lv[j] = f2bf(z - bf2f(h));
        }
        size_t base = ((size_t)blockIdx.x * MTOK + m) * HIDD + c0;
        *(u16x8*)&z_hi[base] = hv;
        *(u16x8*)&z_lo[base] = lv;
    }
}

// ---------------- full f32 mixer for the (uniform) t=0 row ----------------
__global__ __launch_bounds__(256) void mixer_kernel(
        const float* __restrict__ ln1_g, const float* __restrict__ ln1_b,
        const float* __restrict__ tw1, const float* __restrict__ tb1,
        const float* __restrict__ tw2, const float* __restrict__ tb2,
        const float* __restrict__ ln2_g, const float* __restrict__ ln2_b,
        const float* __restrict__ cw1, const float* __restrict__ cb1,
        const float* __restrict__ cw2, const float* __restrict__ cb2,
        float* __restrict__ vout) {
    int tid = threadIdx.x;
    __shared__ __align__(16) float sx[MTOK][HIDD];
    __shared__ __align__(16) float sy[MTOK][HIDD];
    __shared__ float stw1[64], stw2[64], stb1[8], stb2[8];
    if (tid < 64) { stw1[tid] = tw1[tid]; stw2[tid] = tw2[tid]; }
    if (tid < 8)  { stb1[tid] = tb1[tid]; stb2[tid] = tb2[tid]; }
    __syncthreads();
    float b1v = ln1_b[tid];
    float ty[MTOK];
    #pragma unroll
    for (int m = 0; m < MTOK; m++) ty[m] = b1v;
    float u[MTOK];
    #pragma unroll
    for (int k = 0; k < MTOK; k++) {
        float a = stb1[k];
        #pragma unroll
        for (int m = 0; m < MTOK; m++) a = fmaf(ty[m], stw1[m * MTOK + k], a);
        u[k] = gelu_f(a);
    }
    #pragma unroll
    for (int k = 0; k < MTOK; k++) {
        float a = stb2[k];
        #pragma unroll
        for (int m = 0; m < MTOK; m++) a = fmaf(u[m], stw2[m * MTOK + k], a);
        sx[k][tid] = a;
    }
    __syncthreads();
    __shared__ float red[MTOK][2];
    int wave = tid >> 6, lane = tid & 63;
    float g2v = ln2_g[tid], b2v = ln2_b[tid];
    #pragma unroll
    for (int rep = 0; rep < 2; rep++) {
        int m = wave + rep * 4;
        float x0 = sx[m][lane], x1 = sx[m][lane + 64], x2 = sx[m][lane + 128], x3 = sx[m][lane + 192];
        float s = x0 + x1 + x2 + x3;
        float ss = x0 * x0 + x1 * x1 + x2 * x2 + x3 * x3;
        for (int off = 32; off > 0; off >>= 1) { s += __shfl_down(s, off, 64); ss += __shfl_down(ss, off, 64); }
        if (lane == 0) {
            float mu = s * (1.f / HIDD);
            float var = ss * (1.f / HIDD) - mu * mu;
            red[m][0] = mu;
            red[m][1] = rsqrtf(var + LNEPS);
        }
    }
    __syncthreads();
    #pragma unroll
    for (int m = 0; m < MTOK; m++) sy[m][tid] = (sx[m][tid] - red[m][0]) * red[m][1] * g2v + b2v;
    __syncthreads();
    float acc[MTOK];
    #pragma unroll
    for (int m = 0; m < MTOK; m++) acc[m] = 0.f;
    for (int h = 0; h < HIDD; h += 4) {
        float w0 = cw1[(h + 0) * HIDD + tid];
        float w1 = cw1[(h + 1) * HIDD + tid];
        float w2 = cw1[(h + 2) * HIDD + tid];
        float w3 = cw1[(h + 3) * HIDD + tid];
        #pragma unroll
        for (int m = 0; m < MTOK; m++) {
            const float4 a = *(const float4*)&sy[m][h];
            acc[m] = fmaf(a.x, w0, acc[m]);
            acc[m] = fmaf(a.y, w1, acc[m]);
            acc[m] = fmaf(a.z, w2, acc[m]);
            acc[m] = fmaf(a.w, w3, acc[m]);
        }
    }
    __syncthreads();
    float cb1v = cb1[tid];
    #pragma unroll
    for (int m = 0; m < MTOK; m++) sy[m][tid] = gelu_f(acc[m] + cb1v);
    __syncthreads();
    float acc2[MTOK];
    #pragma unroll
    for (int m = 0; m < MTOK; m++) acc2[m] = 0.f;
    for (int h = 0; h < HIDD; h += 4) {
        float w0 = cw2[(h + 0) * HIDD + tid];
        float w1 = cw2[(h + 1) * HIDD + tid];
        float w2 = cw2[(h + 2) * HIDD + tid];
        float w3 = cw2[(h + 3) * HIDD + tid];
        #pragma unroll
        for (int m = 0; m < MTOK; m++) {
            const float4 a = *(const float4*)&sy[m][h];
            acc2[m] = fmaf(a.x, w0, acc2[m]);
            acc2[m] = fmaf(a.y, w1, acc2[m]);
            acc2[m] = fmaf(a.z, w2, acc2[m]);
            acc2[m] = fmaf(a.w, w3, acc2[m]);
        }
    }
    float cb2v = cb2[tid];
    float ssum = 0.f;
    #pragma unroll
    for (int m = 0; m < MTOK; m++) ssum += sx[m][tid] + acc2[m] + cb2v;
    vout[tid] = ssum * (1.f / MTOK);
}

// ---------------- fused t=0 head ----------------
__global__ __launch_bounds__(256) void t0_head(const float* __restrict__ v0row,
        const float* __restrict__ pred_w, const float* __restrict__ pred_b,
        const float* __restrict__ cls1_w, const float* __restrict__ cls1_b,
        const float* __restrict__ cls2_w, const float* __restrict__ cls2_b,
        float* __restrict__ h0row, float* __restrict__ y0row) {
    __shared__ float s[HIDD], s2[HIDD];
    int tid = threadIdx.x;
    s[tid] = v0row[tid];
    __syncthreads();
    float a = 0.f;
    for (int k = 0; k < HIDD; k++) a = fmaf(s[k], pred_w[k * HIDD + tid], a);
    float h = tanhf(a + pred_b[tid]);
    h0row[tid] = h;
    s2[tid] = h;
    __syncthreads();
    a = 0.f;
    for (int k = 0; k < HIDD; k++) a = fmaf(s2[k], cls1_w[k * HIDD + tid], a);
    float g = a + cls1_b[tid];
    __syncthreads();
    s[tid] = g;
    __syncthreads();
    if (tid < OUTD) {
        float y = 0.f;
        for (int k = 0; k < HIDD; k++) y = fmaf(s[k], cls2_w[k * OUTD + tid], y);
        y0row[tid] = fmaxf(y + cls2_b[tid], 0.f);
    }
}

__global__ void bcast_both(const float* __restrict__ h0row, const float* __restrict__ y0row,
        float* __restrict__ hout, float* __restrict__ yout) {
    int n = blockIdx.x, tid = threadIdx.x;
    hout[(size_t)n * HIDD + tid] = h0row[tid];
    if (tid < OUTD) yout[(size_t)n * OUTD + tid] = y0row[tid];
}

extern "C" void kernel_launch(void* const* d_in, const int* in_sizes, int n_in,
                              void* d_out, int out_size, void* d_ws, size_t ws_size,
                              hipStream_t stream) {
    const int* edge    = (const int*)d_in[0];
    const int* node_t  = (const int*)d_in[1];
    const float* emb   = (const float*)d_in[3];
    const float* gcn_w1 = (const float*)d_in[4];
    const float* gcn_b1 = (const float*)d_in[5];
    const float* gcn_w2 = (const float*)d_in[6];
    const float* gcn_b2 = (const float*)d_in[7];
    const float* ln1_g = (const float*)d_in[8];
    const float* ln1_b = (const float*)d_in[9];
    const float* tw1   = (const float*)d_in[10];
    const float* tb1   = (const float*)d_in[11];
    const float* tw2   = (const float*)d_in[12];
    const float* tb2   = (const float*)d_in[13];
    const float* ln2_g = (const float*)d_in[14];
    const float* ln2_b = (const float*)d_in[15];
    const float* cw1   = (const float*)d_in[16];
    const float* cb1   = (const float*)d_in[17];
    const float* cw2   = (const float*)d_in[18];
    const float* cb2   = (const float*)d_in[19];
    const float* pred_w = (const float*)d_in[20];
    const float* pred_b = (const float*)d_in[21];
    const float* cls1_w = (const float*)d_in[22];
    const float* cls1_b = (const float*)d_in[23];
    const float* cls2_w = (const float*)d_in[24];
    const float* cls2_b = (const float*)d_in[25];

    const size_t NH = (size_t)NN * HIDD;
    char* wsb = (char*)d_ws;
    size_t off = 0;
    auto alloc = [&](size_t bytes) { char* p = wsb + off; off = (off + bytes + 255) & ~(size_t)255; return p; };
    float* xs   = (float*)alloc(2 * NH * 4);
    u16* v_hi   = (u16*)alloc(2 * NH * 2);         // GCN alias: agg_hi
    u16* v_lo   = (u16*)alloc(2 * NH * 2);         // GCN alias: agg_lo
    u16* h_hi   = (u16*)alloc(2 * NH * 2);         // PREP/GCN alias: xw (f32)
    u16* h_lo   = (u16*)alloc(2 * NH * 2);         // PREP alias: emb_hi+emb_lo
    float* xw2  = (float*)alloc(2 * NH * 4);       // GCN scratch; MIXER alias: s2
    float* xsum = (float*)alloc(2 * NH * 4);
    u16* Bt_all = (u16*)alloc((size_t)6 * 256 * 768 * 2);
    u16* Bt_cw1  = Bt_all;
    u16* Bt_cw2  = Bt_all + 1 * 256 * 768;
    u16* Bt_pred = Bt_all + 2 * 256 * 768;
    u16* Bt_cls1 = Bt_all + 3 * 256 * 768;
    u16* Bt_gw1  = Bt_all + 4 * 256 * 768;
    u16* Bt_gw2  = Bt_all + 5 * 256 * 768;
    float* dinv  = (float*)alloc(2 * NN * 4);
    float* zeros = (float*)alloc(HIDD * 4);
    float* v0row = (float*)alloc(HIDD * 4);
    float* h0row = (float*)alloc(HIDD * 4);
    float* y0row = (float*)alloc(16 * 4);
    int* cnt    = (int*)alloc(2 * NN * 4);
    int* rowst  = (int*)alloc(2 * NN * 4);
    int* cursor = (int*)alloc(2 * NN * 4);
    int* esrc   = (int*)alloc((size_t)2 * EE * 4);
    float* xw    = (float*)h_hi;
    u16*  emb_hi = h_lo;
    u16*  emb_lo = h_lo + NH;
    u16*  agg_hi = v_hi;
    u16*  agg_lo = v_lo;
    u16*  s2_hi  = (u16*)xw2;
    u16*  s2_lo  = (u16*)xw2 + 2 * NH;
    size_t remain = (ws_size > off + 4096) ? (ws_size - off - 4096) : 0;
    int CHN = (int)(remain / 8192);
    if (CHN > 2 * NN) CHN = 2 * NN;
    CHN &= ~15;
    if (CHN < 16) CHN = 16;
    const size_t ZE = (size_t)CHN * MTOK * HIDD;
    u16* z_hi  = (u16*)alloc(ZE * 2);
    u16* z_lo  = (u16*)alloc(ZE * 2);

    float* h_out = (float*)d_out;
    float* y_out = h_out + (size_t)TT * NH;

    // ---- prep ----
    hipMemsetAsync(zeros, 0, HIDD * sizeof(float), stream);
    wsplit_all<<<dim3(256, 6), 256, 0, stream>>>(cw1, cw2, pred_w, cls1_w, gcn_w1, gcn_w2, Bt_all);
    split_kernel<<<(NN * HIDD + 255) / 256, 256, 0, stream>>>(emb, emb_hi, emb_lo, NN * HIDD);
    gemm_split<0, 1, 0, 0><<<2 * ((NN + 127) / 128), 256, 0, stream>>>(
        emb_hi, emb_lo, Bt_gw1, zeros, xw, nullptr, nullptr, nullptr, NN);

    // ---- t=0 outputs (uniform) ----
    mixer_kernel<<<1, 256, 0, stream>>>(ln1_g, ln1_b, tw1, tb1, tw2, tb2,
        ln2_g, ln2_b, cw1, cb1, cw2, cb2, v0row);
    t0_head<<<1, 256, 0, stream>>>(v0row, pred_w, pred_b, cls1_w, cls1_b,
        cls2_w, cls2_b, h0row, y0row);
    bcast_both<<<NN, 256, 0, stream>>>(h0row, y0row, h_out, y_out);

    // ---- GCN for both timesteps (batched) ----
    hipMemsetAsync(cnt, 0, 2 * NN * sizeof(int), stream);
    count_kernel<<<dim3((EE + 255) / 256, 2), 256, 0, stream>>>(edge, cnt);
    scan_kernel<<<2, 1024, 0, stream>>>(cnt, rowst, cursor, dinv);
    fill_kernel<<<dim3((EE + 255) / 256, 2), 256, 0, stream>>>(edge, cursor, esrc);
    gcn_agg<1, 0, 1><<<dim3((NN + 3) / 4, 2), 256, 0, stream>>>(xw, 0,
        esrc, rowst, cnt, dinv, gcn_b1, nullptr, agg_hi, agg_lo);
    gemm_split<0, 1, 0, 0><<<2 * ((2 * NN + 127) / 128), 256, 0, stream>>>(
        agg_hi, agg_lo, Bt_gw2, zeros, xw2, nullptr, nullptr, nullptr, 2 * NN);
    gcn_agg<0, 1, 0><<<dim3((NN + 3) / 4, 2), 256, 0, stream>>>(xw2, NH,
        esrc, rowst, cnt, dinv, gcn_b2, xs, nullptr, nullptr);
    mask_kernel<<<dim3(AA, 2), 256, 0, stream>>>(node_t, xs);

    // ---- mixer for t=1,2: front + cw1 (fused gelu+token-sum epilogue) ----
    for (int nb = 0; nb < 2 * NN; nb += CHN) {
        int nodes = 2 * NN - nb < CHN ? 2 * NN - nb : CHN;
        int R = nodes * MTOK;
        int rb = (R + 127) / 128;
        mixer_front<<<nodes, 256, 0, stream>>>(xs, nb,
            ln1_g, ln1_b, tw1, tb1, tw2, tb2, ln2_g, ln2_b, z_hi, z_lo, xsum);
        gemm_split<1, 0, 0, 1><<<2 * rb, 256, 0, stream>>>(
            z_hi, z_lo, Bt_cw1, cb1, nullptr,
            s2_hi + (size_t)nb * HIDD, s2_lo + (size_t)nb * HIDD, nullptr, R);
    }
    // ---- fused tail: cw2 (+mean fold) -> pred -> cls1 -> cls2, one dispatch ----
    tail_fused<<<(2 * NN + 31) / 32, 512, 0, stream>>>(
        s2_hi, s2_lo, xsum,
        Bt_cw2, cb2, Bt_pred, pred_b, Bt_cls1, cls1_b, cls2_w, cls2_b,
        h_out + NH, y_out + (size_t)NN * OUTD, 2 * NN);
}